// Round 1
// baseline (431.078 us; speedup 1.0000x reference)
//
#include <hip/hip_runtime.h>
#include <hip/hip_bf16.h>
#include <stdint.h>

#define B_  4
#define S_  2048
#define D_  1024
#define H_  16
#define HD_ 64
#define M_  (B_*S_)     // 8192

typedef __bf16 bf16_t;
typedef __bf16 bf16x8 __attribute__((ext_vector_type(8)));
typedef __bf16 bf16x4 __attribute__((ext_vector_type(4)));
typedef float  f32x4  __attribute__((ext_vector_type(4)));

// -------------------- conversions --------------------
__global__ void cvt_f32_to_bf16(const float* __restrict__ src, bf16_t* __restrict__ dst, int n) {
  int stride = gridDim.x * blockDim.x * 4;
  for (int i = (blockIdx.x * blockDim.x + threadIdx.x) * 4; i < n; i += stride) {
    float4 v = *(const float4*)(src + i);
    bf16x4 o = { (bf16_t)v.x, (bf16_t)v.y, (bf16_t)v.z, (bf16_t)v.w };
    *(bf16x4*)(dst + i) = o;
  }
}

// transpose-convert W_q/W_k/W_v (D x D fp32) -> dst rows [3*D][D] bf16, dst[j][k] = W[k][j]
__global__ void cvt_transpose_w(const float* __restrict__ wq, const float* __restrict__ wk,
                                const float* __restrict__ wv, bf16_t* __restrict__ dst) {
  __shared__ float t[32][33];
  int w = blockIdx.z;
  const float* src = (w == 0) ? wq : (w == 1) ? wk : wv;
  int c0 = blockIdx.x * 32, r0 = blockIdx.y * 32;
  int tx = threadIdx.x, ty = threadIdx.y;
#pragma unroll
  for (int i = 0; i < 4; i++)
    t[ty + i * 8][tx] = src[(size_t)(r0 + ty + i * 8) * D_ + c0 + tx];
  __syncthreads();
#pragma unroll
  for (int i = 0; i < 4; i++)
    dst[(size_t)(w * D_ + c0 + ty + i * 8) * D_ + r0 + tx] = (bf16_t)t[tx][ty + i * 8];
}

// -------------------- NT GEMM: C[M,N] = A[M,K] * Bt[N,K]^T (bf16 in, fp32 acc) --------------------
// 128x128 tile, BK=32, 256 threads = 4 waves in 2x2, each wave 64x64 (4x4 16x16 frags)
template <typename OutT>
__global__ void gemm_nt(const bf16_t* __restrict__ A, const bf16_t* __restrict__ Bt,
                        OutT* __restrict__ C, int Mt, int N, int K) {
  __shared__ bf16_t As[128 * 32];
  __shared__ bf16_t Bs[128 * 32];
  const int bn = blockIdx.x, bm = blockIdx.y;
  const int tid = threadIdx.x;
  const int wv = tid >> 6, lane = tid & 63;
  const int wr = wv >> 1, wc = wv & 1;
  const int g = lane >> 4, r16 = lane & 15;
  const int m0 = bm * 128, n0 = bn * 128;

  f32x4 acc[4][4] = {};

  for (int kt = 0; kt < K; kt += 32) {
#pragma unroll
    for (int c = 0; c < 2; c++) {   // stage A: 8 chunks of 1KB, 2 per wave
      int ch = wv * 2 + c;
      int o = ch * 1024 + lane * 16;          // linear byte offset in tile
      int row = o >> 6, colb = o & 63;        // 64B rows
      const bf16_t* gA = A + (size_t)(m0 + row) * K + kt + (colb >> 1);
      __builtin_amdgcn_global_load_lds((const __attribute__((address_space(1))) void*)gA,
          (__attribute__((address_space(3))) void*)((char*)As + ch * 1024), 16, 0, 0);
    }
#pragma unroll
    for (int c = 0; c < 2; c++) {   // stage Bt
      int ch = wv * 2 + c;
      int o = ch * 1024 + lane * 16;
      int row = o >> 6, colb = o & 63;
      const bf16_t* gB = Bt + (size_t)(n0 + row) * K + kt + (colb >> 1);
      __builtin_amdgcn_global_load_lds((const __attribute__((address_space(1))) void*)gB,
          (__attribute__((address_space(3))) void*)((char*)Bs + ch * 1024), 16, 0, 0);
    }
    __syncthreads();

    bf16x8 af[4], bf[4];
#pragma unroll
    for (int i = 0; i < 4; i++) {
      int row = wr * 64 + i * 16 + r16;
      af[i] = *(const bf16x8*)(As + row * 32 + g * 8);
    }
#pragma unroll
    for (int j = 0; j < 4; j++) {
      int row = wc * 64 + j * 16 + r16;
      bf[j] = *(const bf16x8*)(Bs + row * 32 + g * 8);
    }
#pragma unroll
    for (int i = 0; i < 4; i++)
#pragma unroll
      for (int j = 0; j < 4; j++)
        acc[i][j] = __builtin_amdgcn_mfma_f32_16x16x32_bf16(af[i], bf[j], acc[i][j], 0, 0, 0);
    __syncthreads();
  }

#pragma unroll
  for (int i = 0; i < 4; i++)
#pragma unroll
    for (int j = 0; j < 4; j++)
#pragma unroll
      for (int rr = 0; rr < 4; rr++) {
        int grow = m0 + wr * 64 + i * 16 + g * 4 + rr;
        int gcol = n0 + wc * 64 + j * 16 + r16;
        C[(size_t)grow * N + gcol] = (OutT)acc[i][j][rr];
      }
}

// -------------------- flash attention --------------------
// grid: (S/64, B*H); block 256 = 4 waves, each wave owns 16 q rows.
// QKV rows [M_][3072]: cols 0..1023 Q, 1024..2047 K, 2048..3071 V (per-head h at h*64)
__global__ void attn_kernel(const bf16_t* __restrict__ QKV, bf16_t* __restrict__ AO) {
  const int qt = blockIdx.x;
  const int bh = blockIdx.y;
  const int b = bh >> 4, h = bh & 15;
  const int tid = threadIdx.x, wv = tid >> 6, lane = tid & 63;
  const int g = lane >> 4, r16 = lane & 15;

  __shared__ bf16_t Ks[64 * 64];       // row-major [64][64], 16B-chunk XOR swizzled
  __shared__ bf16_t Vt[64 * 72];       // transposed V: Vt[d][k], pad to 72
  __shared__ bf16_t Ps[4][16 * 40];    // per-wave P staging, pad to 40

  const size_t rowbase = (size_t)b * S_;
  const bf16_t* Qg = QKV + (rowbase + qt * 64) * 3072 + h * HD_;
  const bf16_t* Kg = QKV + rowbase * 3072 + 1024 + h * HD_;
  const bf16_t* Vg = QKV + rowbase * 3072 + 2048 + h * HD_;

  // Q fragments: wave's 16 rows x 64 d
  bf16x8 qf[2];
  {
    int row = wv * 16 + r16;
    const bf16_t* p = Qg + (size_t)row * 3072;
    qf[0] = *(const bf16x8*)(p + g * 8);
    qf[1] = *(const bf16x8*)(p + 32 + g * 8);
  }

  f32x4 o_acc[4] = {};
  float mrow[4], lrow[4];
#pragma unroll
  for (int r = 0; r < 4; r++) { mrow[r] = -1e30f; lrow[r] = 0.f; }
  const int qg_row = qt * 64 + wv * 16 + g * 4;
  const float sscale = 0.125f * 1.44269504088896f;  // 1/sqrt(64) * log2(e)

  const int ntiles = qt + 1;
  for (int t = 0; t < ntiles; t++) {
    const int kv0 = t * 64;
    // stage K via global_load_lds, source pre-swizzled: LDS(row,ch) holds global chunk ch^(row&7)
#pragma unroll
    for (int c = 0; c < 2; c++) {
      int chunkid = wv * 2 + c;
      int o = chunkid * 1024 + lane * 16;
      int row = o >> 7;                 // 128B rows
      int ch = (o >> 4) & 7;
      const bf16_t* src = Kg + (size_t)(kv0 + row) * 3072 + ((ch ^ (row & 7)) * 8);
      __builtin_amdgcn_global_load_lds((const __attribute__((address_space(1))) void*)src,
          (__attribute__((address_space(3))) void*)((char*)Ks + chunkid * 1024), 16, 0, 0);
    }
    // stage V transposed (reg staging, scalar LDS writes)
#pragma unroll
    for (int tsk = tid; tsk < 512; tsk += 256) {
      int row = tsk >> 3, c8 = tsk & 7;
      bf16x8 v = *(const bf16x8*)(Vg + (size_t)(kv0 + row) * 3072 + c8 * 8);
#pragma unroll
      for (int j = 0; j < 8; j++)
        Vt[(c8 * 8 + j) * 72 + row] = v[j];
    }
    __syncthreads();

    const bool diag = (t == qt);
#pragma unroll
    for (int kh = 0; kh < 2; kh++) {
      f32x4 s[2];
#pragma unroll
      for (int sub2 = 0; sub2 < 2; sub2++) {
        int krow = (kh * 2 + sub2) * 16 + r16;
        bf16x8 k0 = *(const bf16x8*)((char*)Ks + krow * 128 + ((g) ^ (krow & 7)) * 16);
        bf16x8 k1 = *(const bf16x8*)((char*)Ks + krow * 128 + ((4 + g) ^ (krow & 7)) * 16);
        f32x4 z = {};
        z = __builtin_amdgcn_mfma_f32_16x16x32_bf16(qf[0], k0, z, 0, 0, 0);
        z = __builtin_amdgcn_mfma_f32_16x16x32_bf16(qf[1], k1, z, 0, 0, 0);
        s[sub2] = z;
      }
      // scale + causal mask (only on the diagonal tile)
#pragma unroll
      for (int sub2 = 0; sub2 < 2; sub2++) {
        int kcol = kv0 + (kh * 2 + sub2) * 16 + r16;
#pragma unroll
        for (int rr = 0; rr < 4; rr++) {
          float v = s[sub2][rr] * sscale;
          if (diag && kcol > qg_row + rr) v = -1e30f;
          s[sub2][rr] = v;
        }
      }
      // per-row max over the 16-lane group
      float sc[4];
#pragma unroll
      for (int rr = 0; rr < 4; rr++) {
        float v = fmaxf(s[0][rr], s[1][rr]);
        v = fmaxf(v, __shfl_xor(v, 1));
        v = fmaxf(v, __shfl_xor(v, 2));
        v = fmaxf(v, __shfl_xor(v, 4));
        v = fmaxf(v, __shfl_xor(v, 8));
        float mnew = fmaxf(mrow[rr], v);
        sc[rr] = exp2f(mrow[rr] - mnew);
        mrow[rr] = mnew;
        lrow[rr] *= sc[rr];
      }
#pragma unroll
      for (int c = 0; c < 4; c++)
#pragma unroll
        for (int rr = 0; rr < 4; rr++) o_acc[c][rr] *= sc[rr];
      // p = exp2(s - m); per-lane partial row sums; P -> LDS (bf16)
#pragma unroll
      for (int sub2 = 0; sub2 < 2; sub2++)
#pragma unroll
        for (int rr = 0; rr < 4; rr++) {
          float p = exp2f(s[sub2][rr] - mrow[rr]);
          lrow[rr] += p;
          Ps[wv][(g * 4 + rr) * 40 + sub2 * 16 + r16] = (bf16_t)p;
        }
      // read P as MFMA A-fragment, PV accumulate
      bf16x8 pf = *(const bf16x8*)(&Ps[wv][r16 * 40 + g * 8]);
#pragma unroll
      for (int c = 0; c < 4; c++) {
        bf16x8 vf = *(const bf16x8*)(Vt + (16 * c + r16) * 72 + kh * 32 + g * 8);
        o_acc[c] = __builtin_amdgcn_mfma_f32_16x16x32_bf16(pf, vf, o_acc[c], 0, 0, 0);
      }
    }
    __syncthreads();
  }

  // epilogue: finish row sums, normalize, write AO (bf16, [M_][D_])
  float linv[4];
#pragma unroll
  for (int rr = 0; rr < 4; rr++) {
    float v = lrow[rr];
    v += __shfl_xor(v, 1);
    v += __shfl_xor(v, 2);
    v += __shfl_xor(v, 4);
    v += __shfl_xor(v, 8);
    linv[rr] = 1.0f / v;
  }
  const int arow = qt * 64 + wv * 16 + g * 4;
#pragma unroll
  for (int c = 0; c < 4; c++)
#pragma unroll
    for (int rr = 0; rr < 4; rr++)
      AO[(size_t)(b * S_ + arow + rr) * D_ + h * HD_ + 16 * c + r16] =
          (bf16_t)(o_acc[c][rr] * linv[rr]);
}

// -------------------- launch --------------------
extern "C" void kernel_launch(void* const* d_in, const int* in_sizes, int n_in,
                              void* d_out, int out_size, void* d_ws, size_t ws_size,
                              hipStream_t stream) {
  const float* x  = (const float*)d_in[0];
  const float* Wq = (const float*)d_in[1];
  const float* Wk = (const float*)d_in[2];
  const float* Wv = (const float*)d_in[3];
  const float* Wo = (const float*)d_in[4];
  float* out = (float*)d_out;

  char* ws = (char*)d_ws;
  bf16_t* xb   = (bf16_t*)(ws);                        // 16,777,216 B
  bf16_t* wqkv = (bf16_t*)(ws + 16777216);             //  6,291,456 B  (rows: WqT | WkT | WvT)
  bf16_t* wo   = (bf16_t*)(ws + 16777216 + 6291456);   //  2,097,152 B
  bf16_t* qkv  = (bf16_t*)(ws + 25165824);             // 50,331,648 B  [8192][3072]
  bf16_t* ao   = (bf16_t*)(ws + 75497472);             // 16,777,216 B  [8192][1024]

  cvt_f32_to_bf16<<<1024, 256, 0, stream>>>(x, xb, M_ * D_);
  cvt_f32_to_bf16<<<512, 256, 0, stream>>>(Wo, wo, D_ * D_);
  cvt_transpose_w<<<dim3(32, 32, 3), dim3(32, 8), 0, stream>>>(Wq, Wk, Wv, wqkv);

  // fused QKV projection: [8192,3072] = xb @ wqkvT^T
  gemm_nt<bf16_t><<<dim3(3072 / 128, M_ / 128), 256, 0, stream>>>(xb, wqkv, qkv, M_, 3072, D_);

  attn_kernel<<<dim3(S_ / 64, B_ * H_), 256, 0, stream>>>(qkv, ao);

  // output projection: out = ao @ Wo^T  (fp32 out)
  gemm_nt<float><<<dim3(D_ / 128, M_ / 128), 256, 0, stream>>>(ao, wo, out, M_, D_, D_);
}

// Round 2
// 242.522 us; speedup vs baseline: 1.7775x; 1.7775x over previous
//
#include <hip/hip_runtime.h>
#include <hip/hip_bf16.h>
#include <stdint.h>

#define B_  4
#define S_  2048
#define D_  1024
#define H_  16
#define HD_ 64
#define M_  (B_*S_)     // 8192

typedef __bf16 bf16_t;
typedef __bf16 bf16x8 __attribute__((ext_vector_type(8)));
typedef __bf16 bf16x4 __attribute__((ext_vector_type(4)));
typedef float  f32x4  __attribute__((ext_vector_type(4)));

// -------------------- conversions --------------------
__global__ void cvt_f32_to_bf16(const float* __restrict__ src, bf16_t* __restrict__ dst, int n) {
  int stride = gridDim.x * blockDim.x * 4;
  for (int i = (blockIdx.x * blockDim.x + threadIdx.x) * 4; i < n; i += stride) {
    float4 v = *(const float4*)(src + i);
    bf16x4 o = { (bf16_t)v.x, (bf16_t)v.y, (bf16_t)v.z, (bf16_t)v.w };
    *(bf16x4*)(dst + i) = o;
  }
}

// transpose-convert W_q/W_k/W_v (D x D fp32) -> dst rows [3*D][D] bf16, dst[j][k] = W[k][j]
__global__ void cvt_transpose_w(const float* __restrict__ wq, const float* __restrict__ wk,
                                const float* __restrict__ wv, bf16_t* __restrict__ dst) {
  __shared__ float t[32][33];
  int w = blockIdx.z;
  const float* src = (w == 0) ? wq : (w == 1) ? wk : wv;
  int c0 = blockIdx.x * 32, r0 = blockIdx.y * 32;
  int tx = threadIdx.x, ty = threadIdx.y;
#pragma unroll
  for (int i = 0; i < 4; i++)
    t[ty + i * 8][tx] = src[(size_t)(r0 + ty + i * 8) * D_ + c0 + tx];
  __syncthreads();
#pragma unroll
  for (int i = 0; i < 4; i++)
    dst[(size_t)(w * D_ + c0 + ty + i * 8) * D_ + r0 + tx] = (bf16_t)t[tx][ty + i * 8];
}

// -------------------- NT GEMM: C[M,N] = A[M,K] * Bt[N,K]^T (bf16 in, fp32 acc) --------------------
template <typename OutT>
__global__ void gemm_nt(const bf16_t* __restrict__ A, const bf16_t* __restrict__ Bt,
                        OutT* __restrict__ C, int Mt, int N, int K) {
  __shared__ bf16_t As[128 * 32];
  __shared__ bf16_t Bs[128 * 32];
  const int bn = blockIdx.x, bm = blockIdx.y;
  const int tid = threadIdx.x;
  const int wv = tid >> 6, lane = tid & 63;
  const int wr = wv >> 1, wc = wv & 1;
  const int g = lane >> 4, r16 = lane & 15;
  const int m0 = bm * 128, n0 = bn * 128;

  f32x4 acc[4][4] = {};

  for (int kt = 0; kt < K; kt += 32) {
#pragma unroll
    for (int c = 0; c < 2; c++) {
      int ch = wv * 2 + c;
      int o = ch * 1024 + lane * 16;
      int row = o >> 6, colb = o & 63;
      const bf16_t* gA = A + (size_t)(m0 + row) * K + kt + (colb >> 1);
      __builtin_amdgcn_global_load_lds((const __attribute__((address_space(1))) void*)gA,
          (__attribute__((address_space(3))) void*)((char*)As + ch * 1024), 16, 0, 0);
    }
#pragma unroll
    for (int c = 0; c < 2; c++) {
      int ch = wv * 2 + c;
      int o = ch * 1024 + lane * 16;
      int row = o >> 6, colb = o & 63;
      const bf16_t* gB = Bt + (size_t)(n0 + row) * K + kt + (colb >> 1);
      __builtin_amdgcn_global_load_lds((const __attribute__((address_space(1))) void*)gB,
          (__attribute__((address_space(3))) void*)((char*)Bs + ch * 1024), 16, 0, 0);
    }
    __syncthreads();

    bf16x8 af[4], bf[4];
#pragma unroll
    for (int i = 0; i < 4; i++) {
      int row = wr * 64 + i * 16 + r16;
      af[i] = *(const bf16x8*)(As + row * 32 + g * 8);
    }
#pragma unroll
    for (int j = 0; j < 4; j++) {
      int row = wc * 64 + j * 16 + r16;
      bf[j] = *(const bf16x8*)(Bs + row * 32 + g * 8);
    }
#pragma unroll
    for (int i = 0; i < 4; i++)
#pragma unroll
      for (int j = 0; j < 4; j++)
        acc[i][j] = __builtin_amdgcn_mfma_f32_16x16x32_bf16(af[i], bf[j], acc[i][j], 0, 0, 0);
    __syncthreads();
  }

#pragma unroll
  for (int i = 0; i < 4; i++)
#pragma unroll
    for (int j = 0; j < 4; j++)
#pragma unroll
      for (int rr = 0; rr < 4; rr++) {
        int grow = m0 + wr * 64 + i * 16 + g * 4 + rr;
        int gcol = n0 + wc * 64 + j * 16 + r16;
        C[(size_t)grow * N + gcol] = (OutT)acc[i][j][rr];
      }
}

// -------------------- flash attention --------------------
// grid: (B*H, S/128) with qt reversed; block 256 = 4 waves, each wave owns 32 q rows
// (2 rowgroups of 16). KV tile = 64 rows.
// Vt layout: V^T [64 d][64 k], word-level XOR swizzle sigma(d) = ((d&7)^(d>>3))<<2
// -> transpose writes conflict-free, b128 reads ~2-way (free), 16B alignment preserved.
__global__ __launch_bounds__(256, 3) void attn_kernel(const bf16_t* __restrict__ QKV,
                                                      bf16_t* __restrict__ AO) {
  const int bh = blockIdx.x;
  const int qt = (int)(gridDim.y - 1 - blockIdx.y);   // longest blocks first
  const int b = bh >> 4, h = bh & 15;
  const int tid = threadIdx.x, wv = tid >> 6, lane = tid & 63;
  const int g = lane >> 4, r16 = lane & 15;

  __shared__ bf16_t Ks[64 * 64];        // [64 k][64 d], 16B-chunk XOR swizzled
  __shared__ bf16_t Vt[64 * 64];        // [64 d][64 k], word XOR swizzled
  __shared__ bf16_t Ps[4][2][16 * 72];  // per-wave, per-rowgroup P staging

  const size_t rowbase = (size_t)b * S_;
  const bf16_t* Qg = QKV + (rowbase + qt * 128) * 3072 + h * HD_;
  const bf16_t* Kg = QKV + rowbase * 3072 + 1024 + h * HD_;
  const bf16_t* Vg = QKV + rowbase * 3072 + 2048 + h * HD_;

  // Q fragments: 2 rowgroups x 16 rows x 64 d
  bf16x8 qf[2][2];
#pragma unroll
  for (int rg = 0; rg < 2; rg++) {
    int row = wv * 32 + rg * 16 + r16;
    const bf16_t* p = Qg + (size_t)row * 3072;
    qf[rg][0] = *(const bf16x8*)(p + g * 8);
    qf[rg][1] = *(const bf16x8*)(p + 32 + g * 8);
  }

  f32x4 o_acc[2][4] = {};
  float mrow[2][4], lrow[2][4];
#pragma unroll
  for (int rg = 0; rg < 2; rg++)
#pragma unroll
    for (int r = 0; r < 4; r++) { mrow[rg][r] = -1e30f; lrow[rg][r] = 0.f; }

  const float sscale = 0.125f * 1.44269504088896f;  // 1/sqrt(64) * log2(e)
  const int ntiles = 2 * qt + 2;

  for (int t = 0; t < ntiles; t++) {
    const int kv0 = t * 64;
    // ---- stage K via global_load_lds, source pre-swizzled by 16B chunk ----
#pragma unroll
    for (int c = 0; c < 2; c++) {
      int chunkid = wv * 2 + c;
      int o = chunkid * 1024 + lane * 16;
      int row = o >> 7;
      int ch = (o >> 4) & 7;
      const bf16_t* src = Kg + (size_t)(kv0 + row) * 3072 + ((ch ^ (row & 7)) * 8);
      __builtin_amdgcn_global_load_lds((const __attribute__((address_space(1))) void*)src,
          (__attribute__((address_space(3))) void*)((char*)Ks + chunkid * 1024), 16, 0, 0);
    }
    // ---- stage V transposed, conflict-free swizzled scalar writes ----
#pragma unroll
    for (int it = 0; it < 2; it++) {
      int tsk = tid + it * 256;
      int k = tsk >> 3, c8 = tsk & 7;
      bf16x8 v = *(const bf16x8*)(Vg + (size_t)(kv0 + k) * 3072 + c8 * 8);
#pragma unroll
      for (int j = 0; j < 8; j++) {
        int d = c8 * 8 + j;
        int word = (k >> 1) ^ ((j ^ c8) << 2);
        Vt[d * 64 + word * 2 + (k & 1)] = v[j];
      }
    }
    __syncthreads();

    // ---- QK^T: all 64 cols, K frags shared across rowgroups ----
    bool skip[2], needmask[2];
    int base_row[2];
#pragma unroll
    for (int rg = 0; rg < 2; rg++) {
      base_row[rg] = qt * 128 + wv * 32 + rg * 16;
      skip[rg] = kv0 > base_row[rg] + 15;
      needmask[rg] = (kv0 + 63) > base_row[rg];
    }
    f32x4 s[2][4];
#pragma unroll
    for (int sub = 0; sub < 4; sub++) {
      int krow = sub * 16 + r16;
      bf16x8 k0 = *(const bf16x8*)((char*)Ks + krow * 128 + ((g ^ (krow & 7)) * 16));
      bf16x8 k1 = *(const bf16x8*)((char*)Ks + krow * 128 + (((4 + g) ^ (krow & 7)) * 16));
#pragma unroll
      for (int rg = 0; rg < 2; rg++) {
        if (skip[rg]) continue;
        f32x4 z = {};
        z = __builtin_amdgcn_mfma_f32_16x16x32_bf16(qf[rg][0], k0, z, 0, 0, 0);
        z = __builtin_amdgcn_mfma_f32_16x16x32_bf16(qf[rg][1], k1, z, 0, 0, 0);
        s[rg][sub] = z;
      }
    }

    // ---- softmax per rowgroup (one pass over all 64 cols) ----
    bf16x8 pf[2][2];
#pragma unroll
    for (int rg = 0; rg < 2; rg++) {
      if (skip[rg]) continue;
#pragma unroll
      for (int sub = 0; sub < 4; sub++) {
        int kcol = kv0 + sub * 16 + r16;
#pragma unroll
        for (int rr = 0; rr < 4; rr++) {
          float v = s[rg][sub][rr] * sscale;
          if (needmask[rg] && kcol > base_row[rg] + g * 4 + rr) v = -1e30f;
          s[rg][sub][rr] = v;
        }
      }
      float sc[4];
#pragma unroll
      for (int rr = 0; rr < 4; rr++) {
        float v = fmaxf(fmaxf(s[rg][0][rr], s[rg][1][rr]), fmaxf(s[rg][2][rr], s[rg][3][rr]));
        v = fmaxf(v, __shfl_xor(v, 1));
        v = fmaxf(v, __shfl_xor(v, 2));
        v = fmaxf(v, __shfl_xor(v, 4));
        v = fmaxf(v, __shfl_xor(v, 8));
        float mnew = fmaxf(mrow[rg][rr], v);
        sc[rr] = exp2f(mrow[rg][rr] - mnew);
        mrow[rg][rr] = mnew;
        lrow[rg][rr] *= sc[rr];
      }
#pragma unroll
      for (int c = 0; c < 4; c++)
#pragma unroll
        for (int rr = 0; rr < 4; rr++) o_acc[rg][c][rr] *= sc[rr];
#pragma unroll
      for (int sub = 0; sub < 4; sub++)
#pragma unroll
        for (int rr = 0; rr < 4; rr++) {
          float p = exp2f(s[rg][sub][rr] - mrow[rg][rr]);
          lrow[rg][rr] += p;
          Ps[wv][rg][(g * 4 + rr) * 72 + sub * 16 + r16] = (bf16_t)p;
        }
      pf[rg][0] = *(const bf16x8*)(&Ps[wv][rg][r16 * 72 + g * 8]);
      pf[rg][1] = *(const bf16x8*)(&Ps[wv][rg][r16 * 72 + 32 + g * 8]);
    }

    // ---- PV: V frags shared across rowgroups ----
#pragma unroll
    for (int kh = 0; kh < 2; kh++) {
#pragma unroll
      for (int c = 0; c < 4; c++) {
        int d = c * 16 + r16;
        int word = (kh * 16 + g * 4) ^ (((d & 7) ^ (d >> 3)) << 2);
        bf16x8 vf = *(const bf16x8*)(Vt + d * 64 + word * 2);
#pragma unroll
        for (int rg = 0; rg < 2; rg++) {
          if (skip[rg]) continue;
          o_acc[rg][c] = __builtin_amdgcn_mfma_f32_16x16x32_bf16(pf[rg][kh], vf, o_acc[rg][c], 0, 0, 0);
        }
      }
    }
    __syncthreads();
  }

  // ---- epilogue ----
#pragma unroll
  for (int rg = 0; rg < 2; rg++) {
    float linv[4];
#pragma unroll
    for (int rr = 0; rr < 4; rr++) {
      float v = lrow[rg][rr];
      v += __shfl_xor(v, 1);
      v += __shfl_xor(v, 2);
      v += __shfl_xor(v, 4);
      v += __shfl_xor(v, 8);
      linv[rr] = 1.0f / v;
    }
    const int arow = qt * 128 + wv * 32 + rg * 16 + g * 4;
#pragma unroll
    for (int c = 0; c < 4; c++)
#pragma unroll
      for (int rr = 0; rr < 4; rr++)
        AO[(size_t)(b * S_ + arow + rr) * D_ + h * HD_ + 16 * c + r16] =
            (bf16_t)(o_acc[rg][c][rr] * linv[rr]);
  }
}

// -------------------- launch --------------------
extern "C" void kernel_launch(void* const* d_in, const int* in_sizes, int n_in,
                              void* d_out, int out_size, void* d_ws, size_t ws_size,
                              hipStream_t stream) {
  const float* x  = (const float*)d_in[0];
  const float* Wq = (const float*)d_in[1];
  const float* Wk = (const float*)d_in[2];
  const float* Wv = (const float*)d_in[3];
  const float* Wo = (const float*)d_in[4];
  float* out = (float*)d_out;

  char* ws = (char*)d_ws;
  bf16_t* xb   = (bf16_t*)(ws);                        // 16 MB
  bf16_t* wqkv = (bf16_t*)(ws + 16777216);             //  6 MB (rows: WqT | WkT | WvT)
  bf16_t* wo   = (bf16_t*)(ws + 16777216 + 6291456);   //  2 MB
  bf16_t* qkv  = (bf16_t*)(ws + 25165824);             // 48 MB [8192][3072]
  bf16_t* ao   = (bf16_t*)(ws + 75497472);             // 16 MB [8192][1024]

  cvt_f32_to_bf16<<<1024, 256, 0, stream>>>(x, xb, M_ * D_);
  cvt_f32_to_bf16<<<512, 256, 0, stream>>>(Wo, wo, D_ * D_);
  cvt_transpose_w<<<dim3(32, 32, 3), dim3(32, 8), 0, stream>>>(Wq, Wk, Wv, wqkv);

  gemm_nt<bf16_t><<<dim3(3072 / 128, M_ / 128), 256, 0, stream>>>(xb, wqkv, qkv, M_, 3072, D_);

  attn_kernel<<<dim3(B_ * H_, S_ / 128), 256, 0, stream>>>(qkv, ao);

  gemm_nt<float><<<dim3(D_ / 128, M_ / 128), 256, 0, stream>>>(ao, wo, out, M_, D_, D_);
}